// Round 10
// baseline (364.388 us; speedup 1.0000x reference)
//
#include <hip/hip_runtime.h>
#include <stdint.h>

#define NQ   8192
#define NB   2
#define KNN  10
#define K1   11                 // top-11 incl. self (dist 0 = global min key); dropped at end
#define NTOT (NB * NQ)
#define NGRP (NTOT / 64)        // 256 query groups
#define IDXMASK 0x1FFFu

// tau: per query, 11th-smallest key over a fixed 1024-point subsample (stride 8)
#define SUBS    1024
#define SSTRIDE 8
#define TW      16              // waves in tau block (1024 threads, 64 queries)
#define CKI(s, c, lane) (((s) * TW + (c)) * 64 + (lane))

// scan: group of 64 queries x 4 blocks; each block scans 2048 candidates
#define HB    4
#define CPB   (NQ / HB)         // 2048
#define TILE  1024
#define WPB   8                 // waves per scan block (512 threads)
#define CPWT  (TILE / WPB)      // 128
#define CAPQ  80                // list capacity per (query, block); mean ~22
#define LSTR  81

static __device__ __forceinline__ uint32_t umin32(uint32_t a, uint32_t b) { return a < b ? a : b; }
static __device__ __forceinline__ uint32_t umax32(uint32_t a, uint32_t b) { return a > b ? a : b; }

static __device__ __forceinline__ void insert11(uint32_t (&l)[K1], uint32_t key) {
#pragma unroll
    for (int s = 0; s < K1; ++s) {
        const uint32_t m = l[s];
        l[s] = umin32(key, m);
        key  = umax32(key, m);
    }
}

// ---------------- kernel 1: per-query tau; also zero out + semaphores ----------------
__global__ __launch_bounds__(1024, 4) void plap_tau(
    const float* __restrict__ p1, uint32_t* __restrict__ tauG,
    uint32_t* __restrict__ sema, float* __restrict__ out)
{
    __shared__ float sx[SUBS], sy[SUBS], sz0[SUBS];    // 12 KB
    __shared__ uint32_t ck[K1 * TW * 64];              // 45056 B

    const int tid  = threadIdx.x;
    const int lane = tid & 63;
    const int wave = tid >> 6;
    const int wq   = __builtin_amdgcn_readfirstlane(wave);
    const int b    = blockIdx.x >> 7;
    const int qi   = ((blockIdx.x & 127) << 6) | lane;
    const float* __restrict__ P = p1 + (size_t)b * NQ * 3;

    if (tid == 0) {
        sema[blockIdx.x] = 0u;                          // per-group semaphore
        if (blockIdx.x == 0) out[0] = 0.0f;             // loss accumulator
    }
    {
        const float* src = P + (size_t)(tid * SSTRIDE) * 3;
        sx[tid] = src[0]; sy[tid] = src[1]; sz0[tid] = src[2];
    }
    const float qx = P[qi * 3 + 0];
    const float qy = P[qi * 3 + 1];
    const float qz = P[qi * 3 + 2];
    __syncthreads();

    uint32_t l[K1];
#pragma unroll
    for (int s = 0; s < K1; ++s) l[s] = 0xFFFFFFFFu;
    const int t0 = wq * (SUBS / TW);
#pragma unroll 4
    for (int t = t0; t < t0 + SUBS / TW; ++t) {
        const float dx = qx - sx[t], dy = qy - sy[t], dz = qz - sz0[t];
        const float d  = fmaf(dx, dx, fmaf(dy, dy, dz * dz));
        insert11(l, (__float_as_uint(d) & ~IDXMASK) | (uint32_t)(t * SSTRIDE));
    }
#pragma unroll
    for (int s = 0; s < K1; ++s) ck[CKI(s, wq, lane)] = l[s];
    __syncthreads();

    for (int st = 1; st < TW; st <<= 1) {
        if ((wq & (2 * st - 1)) == 0) {
            uint32_t A[K1];
#pragma unroll
            for (int s = 0; s < K1; ++s) A[s] = ck[CKI(s, wq, lane)];
#pragma unroll
            for (int e = 0; e < K1; ++e) insert11(A, ck[CKI(e, wq + st, lane)]);
            if (2 * st < TW) {
#pragma unroll
                for (int s = 0; s < K1; ++s) ck[CKI(s, wq, lane)] = A[s];
            } else {
                tauG[blockIdx.x * 64 + lane] = A[K1 - 1];
            }
        }
        __syncthreads();
    }
}

// ---------------- kernel 2: filtered scan + last-arriver merge + loss ----------------
__global__ __launch_bounds__(512, 8) void plap_scan_merge(
    const float* __restrict__ p1, const float* __restrict__ p2,
    const uint32_t* __restrict__ tauG,
    uint32_t* __restrict__ keysG, uint32_t* __restrict__ cntG,
    uint32_t* __restrict__ sema, float* __restrict__ out)
{
    __shared__ float2 sxy[TILE];                       // 8 KB
    __shared__ float  szz[TILE];                       // 4 KB
    __shared__ uint32_t lists[64 * LSTR];              // 20736 B (reused as sk in merge)
    __shared__ uint32_t cnt[64];
    __shared__ uint32_t slast;

    const int tid   = threadIdx.x;
    const int lane  = tid & 63;
    const int wave  = tid >> 6;
    const int wq    = __builtin_amdgcn_readfirstlane(wave);
    const int group = blockIdx.x >> 2;                 // 0..255
    const int hb    = blockIdx.x & 3;
    const int b     = group >> 7;
    const int qi    = ((group & 127) << 6) | lane;
    const int qidG  = group * 64 + lane;
    const float* __restrict__ P = p1 + (size_t)b * NQ * 3;

    const float qx = P[qi * 3 + 0];
    const float qy = P[qi * 3 + 1];
    const float qz = P[qi * 3 + 2];
    const uint32_t tq = tauG[qidG];

    if (tid < 64) cnt[tid] = 0;

    const int j0 = hb * CPB;
    for (int tile = 0; tile < CPB / TILE; ++tile) {
        const int jt = j0 + tile * TILE;
        __syncthreads();
#pragma unroll
        for (int c = tid; c < TILE; c += 512) {
            const float* src = P + (size_t)(jt + c) * 3;
            sxy[c] = make_float2(src[0], src[1]);
            szz[c] = src[2];
        }
        __syncthreads();

        const int c0 = wq * CPWT;
#pragma unroll 8
        for (int t = 0; t < CPWT; ++t) {
            const int c = c0 + t;
            const float2 cc = sxy[c];                  // ds_read_b64 broadcast
            const float dx = qx - cc.x;
            const float dy = qy - cc.y;
            const float dz = qz - szz[c];
            const float d  = fmaf(dx, dx, fmaf(dy, dy, dz * dz));
            const uint32_t key = (__float_as_uint(d) & ~IDXMASK) | (uint32_t)(jt + c);
            if (key <= tq) {
                const uint32_t old = atomicAdd(&cnt[lane], 1u);
                if (old < CAPQ) lists[lane * LSTR + old] = key;
            }
        }
    }
    __syncthreads();

    // write-out lists + counts
    if (tid < 64) cntG[(size_t)qidG * HB + hb] = cnt[tid];
    const uint32_t mycnt = umin32(cnt[lane], CAPQ);
    for (int s = wq; s < (int)mycnt; s += WPB)
        keysG[((size_t)hb * CAPQ + s) * NTOT + qidG] = lists[lane * LSTR + s];

    // release: every thread drains its own global stores device-visibly
    __threadfence();
    __syncthreads();
    if (tid == 0) {
        const uint32_t old = __hip_atomic_fetch_add(&sema[group], 1u,
                                 __ATOMIC_ACQ_REL, __HIP_MEMORY_SCOPE_AGENT);
        slast = (old == HB - 1) ? 1u : 0u;
    }
    __syncthreads();
    if (!slast) return;
    __threadfence();                                    // acquire side

    // ---------------- merge (last-arriving block of this group) ----------------
    const float* __restrict__ P2 = p2 + (size_t)b * NQ * 3;
    uint32_t F[K1];
#pragma unroll
    for (int s = 0; s < K1; ++s) F[s] = 0xFFFFFFFFu;

    if (wq < HB) {
        const uint32_t c = cntG[(size_t)qidG * HB + wq];
        if (c <= CAPQ) {
            for (uint32_t s = 0; s < c; ++s)            // coalesced across lanes
                insert11(F, keysG[((size_t)wq * CAPQ + s) * NTOT + qidG]);
        } else {
            // exact fallback (probability ~0): rescan this quarter
            for (int j = wq * CPB; j < (wq + 1) * CPB; ++j) {
                const float dx = qx - P[j * 3 + 0];
                const float dy = qy - P[j * 3 + 1];
                const float dz = qz - P[j * 3 + 2];
                const float d  = fmaf(dx, dx, fmaf(dy, dy, dz * dz));
                insert11(F, (__float_as_uint(d) & ~IDXMASK) | (uint32_t)j);
            }
        }
#pragma unroll
        for (int s = 0; s < K1; ++s) lists[(wq * K1 + s) * 64 + lane] = F[s];
    }
    for (int st = 1; st < HB; st <<= 1) {
        __syncthreads();
        if (wq < HB && (wq & (2 * st - 1)) == 0) {
#pragma unroll
            for (int e = 0; e < K1; ++e) insert11(F, lists[((wq + st) * K1 + e) * 64 + lane]);
            if (2 * st < HB) {
#pragma unroll
                for (int s = 0; s < K1; ++s) lists[(wq * K1 + s) * 64 + lane] = F[s];
            }
        }
    }

    if (wq == 0) {
        float s1x = 0.f, s1y = 0.f, s1z = 0.f, s2x = 0.f, s2y = 0.f, s2z = 0.f;
#pragma unroll
        for (int s = 1; s < K1; ++s) {                  // F[0] = self (d = 0)
            const int n = (int)(F[s] & IDXMASK);
            s1x += P[n * 3 + 0];  s1y += P[n * 3 + 1];  s1z += P[n * 3 + 2];
            s2x += P2[n * 3 + 0]; s2y += P2[n * 3 + 1]; s2z += P2[n * 3 + 2];
        }
        const float invk = 1.0f / (float)KNN;
        const float lx = (s1x * invk - qx) - (s2x * invk - P2[qi * 3 + 0]);
        const float ly = (s1y * invk - qy) - (s2y * invk - P2[qi * 3 + 1]);
        const float lz = (s1z * invk - qz) - (s2z * invk - P2[qi * 3 + 2]);
        float acc = fabsf(lx) + fabsf(ly) + fabsf(lz);
#pragma unroll
        for (int off = 32; off > 0; off >>= 1)
            acc += __shfl_down(acc, off, 64);
        if (lane == 0) atomicAdd(out, acc * (1.0f / (float)(NTOT * 3)));
    }
}

extern "C" void kernel_launch(void* const* d_in, const int* in_sizes, int n_in,
                              void* d_out, int out_size, void* d_ws, size_t ws_size,
                              hipStream_t stream) {
    const float* p1 = (const float*)d_in[0];
    const float* p2 = (const float*)d_in[1];
    float* out      = (float*)d_out;

    // ws: tau (64 KB) | cnt (256 KB) | sema (1 KB) | keys (HB*CAPQ*NTOT*4 = 21 MB)
    uint32_t* tauG  = (uint32_t*)d_ws;
    uint32_t* cntG  = tauG + NTOT;
    uint32_t* sema  = cntG + (size_t)NTOT * HB;
    uint32_t* keysG = sema + NGRP;

    plap_tau<<<dim3(NGRP), dim3(TW * 64), 0, stream>>>(p1, tauG, sema, out);
    plap_scan_merge<<<dim3(NGRP * HB), dim3(WPB * 64), 0, stream>>>(
        p1, p2, tauG, keysG, cntG, sema, out);
}

// Round 11
// 145.094 us; speedup vs baseline: 2.5114x; 2.5114x over previous
//
#include <hip/hip_runtime.h>
#include <stdint.h>

#define NQ   8192
#define NB   2
#define KNN  10
#define K1   11                 // top-11 incl. self (dist 0 = global min key); dropped at end
#define NTOT (NB * NQ)
#define NGRP (NTOT / 64)        // 256 query groups
#define IDXMASK 0x1FFFu

// tau: per query, 11th-smallest key over a fixed 1024-point subsample (stride 8)
#define SUBS    1024
#define SSTRIDE 8
#define TW      16              // waves in tau block (1024 threads, 64 queries)
#define CKI(s, c, lane) (((s) * TW + (c)) * 64 + (lane))

// scan: group of 64 queries x 4 blocks; each block scans 2048 candidates
#define HB    4
#define CPB   (NQ / HB)         // 2048
#define TILE  1024
#define WPB   8                 // waves per scan block (512 threads)
#define CPWT  (TILE / WPB)      // 128
#define CAPQ  80                // list capacity per (query, block); mean ~22, ~7.8 sigma
#define LSTR  81

static __device__ __forceinline__ uint32_t umin32(uint32_t a, uint32_t b) { return a < b ? a : b; }
static __device__ __forceinline__ uint32_t umax32(uint32_t a, uint32_t b) { return a > b ? a : b; }

static __device__ __forceinline__ void insert11(uint32_t (&l)[K1], uint32_t key) {
#pragma unroll
    for (int s = 0; s < K1; ++s) {
        const uint32_t m = l[s];
        l[s] = umin32(key, m);
        key  = umax32(key, m);
    }
}

// ---------------- kernel 1: per-query tau; also zeroes the loss accumulator ----------------
__global__ __launch_bounds__(1024, 4) void plap_tau(
    const float* __restrict__ p1, uint32_t* __restrict__ tauG, float* __restrict__ out)
{
    __shared__ float sx[SUBS], sy[SUBS], sz0[SUBS];    // 12 KB
    __shared__ uint32_t ck[K1 * TW * 64];              // 45056 B

    const int tid  = threadIdx.x;
    const int lane = tid & 63;
    const int wave = tid >> 6;
    const int wq   = __builtin_amdgcn_readfirstlane(wave);
    const int b    = blockIdx.x >> 7;
    const int qi   = ((blockIdx.x & 127) << 6) | lane;
    const float* __restrict__ P = p1 + (size_t)b * NQ * 3;

    if (blockIdx.x == 0 && tid == 0) out[0] = 0.0f;    // replaces memset dispatch
    {
        const float* src = P + (size_t)(tid * SSTRIDE) * 3;
        sx[tid] = src[0]; sy[tid] = src[1]; sz0[tid] = src[2];
    }
    const float qx = P[qi * 3 + 0];
    const float qy = P[qi * 3 + 1];
    const float qz = P[qi * 3 + 2];
    __syncthreads();

    uint32_t l[K1];
#pragma unroll
    for (int s = 0; s < K1; ++s) l[s] = 0xFFFFFFFFu;
    const int t0 = wq * (SUBS / TW);
#pragma unroll 4
    for (int t = t0; t < t0 + SUBS / TW; ++t) {
        const float dx = qx - sx[t], dy = qy - sy[t], dz = qz - sz0[t];
        const float d  = fmaf(dx, dx, fmaf(dy, dy, dz * dz));
        insert11(l, (__float_as_uint(d) & ~IDXMASK) | (uint32_t)(t * SSTRIDE));
    }
#pragma unroll
    for (int s = 0; s < K1; ++s) ck[CKI(s, wq, lane)] = l[s];
    __syncthreads();

    for (int st = 1; st < TW; st <<= 1) {              // tree-merge -> 11th of 1024
        if ((wq & (2 * st - 1)) == 0) {
            uint32_t A[K1];
#pragma unroll
            for (int s = 0; s < K1; ++s) A[s] = ck[CKI(s, wq, lane)];
#pragma unroll
            for (int e = 0; e < K1; ++e) insert11(A, ck[CKI(e, wq + st, lane)]);
            if (2 * st < TW) {
#pragma unroll
                for (int s = 0; s < K1; ++s) ck[CKI(s, wq, lane)] = A[s];
            } else {
                tauG[blockIdx.x * 64 + lane] = A[K1 - 1];
            }
        }
        __syncthreads();
    }
}

// ---------------- kernel 2: filtered scan, float4 LDS tiles ----------------
__global__ __launch_bounds__(512, 8) void plap_scan(
    const float* __restrict__ p1, const uint32_t* __restrict__ tauG,
    uint32_t* __restrict__ keysG, uint32_t* __restrict__ cntG)
{
    __shared__ float4 stile[TILE];                     // 16 KB
    __shared__ uint32_t lists[64 * LSTR];              // 20736 B
    __shared__ uint32_t cnt[64];                       // -> ~37 KB total (4 blocks/CU)

    const int tid   = threadIdx.x;
    const int lane  = tid & 63;
    const int wave  = tid >> 6;
    const int wq    = __builtin_amdgcn_readfirstlane(wave);
    const int group = blockIdx.x >> 2;                 // 0..255
    const int hb    = blockIdx.x & 3;
    const int b     = group >> 7;
    const int qi    = ((group & 127) << 6) | lane;
    const int qidG  = group * 64 + lane;
    const float* __restrict__ P = p1 + (size_t)b * NQ * 3;

    const float qx = P[qi * 3 + 0];
    const float qy = P[qi * 3 + 1];
    const float qz = P[qi * 3 + 2];
    const uint32_t tq = tauG[qidG];

    if (tid < 64) cnt[tid] = 0;

    const int j0 = hb * CPB;
    for (int tile = 0; tile < CPB / TILE; ++tile) {
        const int jt = j0 + tile * TILE;
        __syncthreads();                               // cnt init / prev tile done
#pragma unroll
        for (int c = tid; c < TILE; c += 512) {        // stage 1024 candidates as float4
            const float* src = P + (size_t)(jt + c) * 3;
            stile[c] = make_float4(src[0], src[1], src[2], 0.0f);
        }
        __syncthreads();

        const int c0 = wq * CPWT;
#pragma unroll 8
        for (int t = 0; t < CPWT; ++t) {
            const int c = c0 + t;
            const float4 cc = stile[c];                // ds_read_b128 broadcast
            const float dx = qx - cc.x;
            const float dy = qy - cc.y;
            const float dz = qz - cc.z;
            const float d  = fmaf(dx, dx, fmaf(dy, dy, dz * dz));
            const uint32_t key = (__float_as_uint(d) & ~IDXMASK) | (uint32_t)(jt + c);
            if (key <= tq) {                           // key-space: exact superset
                const uint32_t old = atomicAdd(&cnt[lane], 1u);
                if (old < CAPQ) lists[lane * LSTR + old] = key;
            }
        }
    }
    __syncthreads();

    // write-out: counts + keys, query-contiguous layout [qid][hb][slot]
    if (tid < 64) cntG[(size_t)qidG * HB + hb] = cnt[tid];
    const uint32_t mycnt = umin32(cnt[lane], CAPQ);
    uint32_t* __restrict__ dst = keysG + (size_t)qidG * (HB * CAPQ) + (size_t)hb * CAPQ;
    for (int s = wq; s < (int)mycnt; s += WPB)
        dst[s] = lists[lane * LSTR + s];
}

// ---------------- kernel 3: parallel merge (4 waves / 64 queries) + loss ----------------
__global__ __launch_bounds__(256) void plap_merge_loss(
    const float* __restrict__ p1, const float* __restrict__ p2,
    const uint32_t* __restrict__ keysG, const uint32_t* __restrict__ cntG,
    float* __restrict__ out)
{
    __shared__ uint32_t sk[HB * K1 * 64];              // 11264 B, lane-major
    const int ql = threadIdx.x & 63;
    const int w  = threadIdx.x >> 6;                   // 0..3 == hb
    const int wu = __builtin_amdgcn_readfirstlane(w);
    const int qid = blockIdx.x * 64 + ql;              // 0..NTOT-1
    const int b   = qid >> 13;
    const int qi  = qid & (NQ - 1);
    const float* __restrict__ P1 = p1 + (size_t)b * NQ * 3;
    const float* __restrict__ P2 = p2 + (size_t)b * NQ * 3;

    const float qx = P1[qi * 3 + 0];
    const float qy = P1[qi * 3 + 1];
    const float qz = P1[qi * 3 + 2];

    uint32_t F[K1];
#pragma unroll
    for (int s = 0; s < K1; ++s) F[s] = 0xFFFFFFFFu;

    const uint32_t c = cntG[(size_t)qid * HB + wu];
    if (c <= CAPQ) {
        // lane-serial contiguous stream: ~2-6 cache lines per lane
        const uint32_t* __restrict__ src =
            keysG + (size_t)qid * (HB * CAPQ) + (size_t)wu * CAPQ;
        for (uint32_t s = 0; s < c; ++s) insert11(F, src[s]);
    } else {
        // exact fallback (probability ~0): rescan this quarter
        for (int j = wu * CPB; j < (wu + 1) * CPB; ++j) {
            const float dx = qx - P1[j * 3 + 0];
            const float dy = qy - P1[j * 3 + 1];
            const float dz = qz - P1[j * 3 + 2];
            const float d  = fmaf(dx, dx, fmaf(dy, dy, dz * dz));
            insert11(F, (__float_as_uint(d) & ~IDXMASK) | (uint32_t)j);
        }
    }

#pragma unroll
    for (int s = 0; s < K1; ++s) sk[(wu * K1 + s) * 64 + ql] = F[s];
    for (int st = 1; st < HB; st <<= 1) {
        __syncthreads();
        if ((wu & (2 * st - 1)) == 0) {
#pragma unroll
            for (int e = 0; e < K1; ++e) insert11(F, sk[((wu + st) * K1 + e) * 64 + ql]);
            if (2 * st < HB) {
#pragma unroll
                for (int s = 0; s < K1; ++s) sk[(wu * K1 + s) * 64 + ql] = F[s];
            }
        }
    }

    if (wu == 0) {
        float s1x = 0.f, s1y = 0.f, s1z = 0.f, s2x = 0.f, s2y = 0.f, s2z = 0.f;
#pragma unroll
        for (int s = 1; s < K1; ++s) {                 // F[0] = self (d = 0)
            const int n = (int)(F[s] & IDXMASK);
            s1x += P1[n * 3 + 0]; s1y += P1[n * 3 + 1]; s1z += P1[n * 3 + 2];
            s2x += P2[n * 3 + 0]; s2y += P2[n * 3 + 1]; s2z += P2[n * 3 + 2];
        }
        const float invk = 1.0f / (float)KNN;
        const float lx = (s1x * invk - qx) - (s2x * invk - P2[qi * 3 + 0]);
        const float ly = (s1y * invk - qy) - (s2y * invk - P2[qi * 3 + 1]);
        const float lz = (s1z * invk - qz) - (s2z * invk - P2[qi * 3 + 2]);
        float acc = fabsf(lx) + fabsf(ly) + fabsf(lz);
#pragma unroll
        for (int off = 32; off > 0; off >>= 1)
            acc += __shfl_down(acc, off, 64);
        if (ql == 0) atomicAdd(out, acc * (1.0f / (float)(NTOT * 3)));
    }
}

extern "C" void kernel_launch(void* const* d_in, const int* in_sizes, int n_in,
                              void* d_out, int out_size, void* d_ws, size_t ws_size,
                              hipStream_t stream) {
    const float* p1 = (const float*)d_in[0];
    const float* p2 = (const float*)d_in[1];
    float* out      = (float*)d_out;

    // ws: tau (64 KB) | cnt (256 KB) | keys (NTOT*HB*CAPQ*4 = 21 MB)
    uint32_t* tauG  = (uint32_t*)d_ws;
    uint32_t* cntG  = tauG + NTOT;
    uint32_t* keysG = cntG + (size_t)NTOT * HB;

    plap_tau <<<dim3(NGRP), dim3(TW * 64), 0, stream>>>(p1, tauG, out);
    plap_scan<<<dim3(NGRP * HB), dim3(WPB * 64), 0, stream>>>(p1, tauG, keysG, cntG);
    plap_merge_loss<<<dim3(NGRP), dim3(256), 0, stream>>>(p1, p2, keysG, cntG, out);
}

// Round 12
// 133.218 us; speedup vs baseline: 2.7353x; 1.0891x over previous
//
#include <hip/hip_runtime.h>
#include <stdint.h>

#define NQ   8192
#define NB   2
#define KNN  10
#define K1   11                 // top-11 incl. self (dist 0 = global min key); dropped at end
#define NTOT (NB * NQ)
#define NGRP (NTOT / 64)        // 256 query groups
#define IDXMASK 0x1FFFu

// tau: per query, 11th-smallest key over a fixed 2048-point subsample (stride 4)
#define SUBS    2048
#define SSTRIDE 4
#define TW      16              // waves in tau block (1024 threads, 64 queries)
#define CKI(s, c, lane) (((s) * TW + (c)) * 64 + (lane))

// scan: group of 64 queries x 4 blocks; each block scans 2048 candidates
#define HB    4
#define CPB   (NQ / HB)         // 2048
#define TILE  1024
#define WPB   8                 // waves per scan block (512 threads)
#define CPWT  (TILE / WPB)      // 128
#define CAPQ  40                // list capacity per (query, block); lambda ~11, P(ovf) ~ 1e-11
#define LSTR  41

static __device__ __forceinline__ uint32_t umin32(uint32_t a, uint32_t b) { return a < b ? a : b; }
static __device__ __forceinline__ uint32_t umax32(uint32_t a, uint32_t b) { return a > b ? a : b; }

static __device__ __forceinline__ void insert11(uint32_t (&l)[K1], uint32_t key) {
#pragma unroll
    for (int s = 0; s < K1; ++s) {
        const uint32_t m = l[s];
        l[s] = umin32(key, m);
        key  = umax32(key, m);
    }
}

// ---------------- kernel 1: per-query tau; also zeroes the loss accumulator ----------------
__global__ __launch_bounds__(1024, 4) void plap_tau(
    const float* __restrict__ p1, uint32_t* __restrict__ tauG, float* __restrict__ out)
{
    __shared__ float sx[SUBS], sy[SUBS], sz0[SUBS];    // 24 KB
    __shared__ uint32_t ck[K1 * TW * 64];              // 45056 B

    const int tid  = threadIdx.x;
    const int lane = tid & 63;
    const int wave = tid >> 6;
    const int wq   = __builtin_amdgcn_readfirstlane(wave);
    const int b    = blockIdx.x >> 7;
    const int qi   = ((blockIdx.x & 127) << 6) | lane;
    const float* __restrict__ P = p1 + (size_t)b * NQ * 3;

    if (blockIdx.x == 0 && tid == 0) out[0] = 0.0f;    // replaces memset dispatch
#pragma unroll
    for (int t = tid; t < SUBS; t += 1024) {
        const float* src = P + (size_t)(t * SSTRIDE) * 3;
        sx[t] = src[0]; sy[t] = src[1]; sz0[t] = src[2];
    }
    const float qx = P[qi * 3 + 0];
    const float qy = P[qi * 3 + 1];
    const float qz = P[qi * 3 + 2];
    __syncthreads();

    uint32_t l[K1];
#pragma unroll
    for (int s = 0; s < K1; ++s) l[s] = 0xFFFFFFFFu;
    const int t0 = wq * (SUBS / TW);                    // 128 samples per wave
#pragma unroll 4
    for (int t = t0; t < t0 + SUBS / TW; ++t) {
        const float dx = qx - sx[t], dy = qy - sy[t], dz = qz - sz0[t];
        const float d  = fmaf(dx, dx, fmaf(dy, dy, dz * dz));
        insert11(l, (__float_as_uint(d) & ~IDXMASK) | (uint32_t)(t * SSTRIDE));
    }
#pragma unroll
    for (int s = 0; s < K1; ++s) ck[CKI(s, wq, lane)] = l[s];
    __syncthreads();

    for (int st = 1; st < TW; st <<= 1) {              // tree-merge -> 11th of 2048
        if ((wq & (2 * st - 1)) == 0) {
            uint32_t A[K1];
#pragma unroll
            for (int s = 0; s < K1; ++s) A[s] = ck[CKI(s, wq, lane)];
#pragma unroll
            for (int e = 0; e < K1; ++e) insert11(A, ck[CKI(e, wq + st, lane)]);
            if (2 * st < TW) {
#pragma unroll
                for (int s = 0; s < K1; ++s) ck[CKI(s, wq, lane)] = A[s];
            } else {
                tauG[blockIdx.x * 64 + lane] = A[K1 - 1];
            }
        }
        __syncthreads();
    }
}

// ---------------- kernel 2: filtered scan, float2+float LDS tiles ----------------
__global__ __launch_bounds__(512, 8) void plap_scan(
    const float* __restrict__ p1, const uint32_t* __restrict__ tauG,
    uint32_t* __restrict__ keysG, uint32_t* __restrict__ cntG)
{
    __shared__ float2 sxy[TILE];                       // 8 KB
    __shared__ float  szz[TILE];                       // 4 KB
    __shared__ uint32_t lists[64 * LSTR];              // 10496 B
    __shared__ uint32_t cnt[64];                       // -> ~23 KB total (4 blocks/CU)

    const int tid   = threadIdx.x;
    const int lane  = tid & 63;
    const int wave  = tid >> 6;
    const int wq    = __builtin_amdgcn_readfirstlane(wave);
    const int group = blockIdx.x >> 2;                 // 0..255
    const int hb    = blockIdx.x & 3;
    const int b     = group >> 7;
    const int qi    = ((group & 127) << 6) | lane;
    const int qidG  = group * 64 + lane;
    const float* __restrict__ P = p1 + (size_t)b * NQ * 3;

    const float qx = P[qi * 3 + 0];
    const float qy = P[qi * 3 + 1];
    const float qz = P[qi * 3 + 2];
    const uint32_t tq  = tauG[qidG];
    const float tauUpF = __uint_as_float(tq | IDXMASK); // pass iff trunc(d) <= trunc(tau)

    if (tid < 64) cnt[tid] = 0;

    const int j0 = hb * CPB;
    for (int tile = 0; tile < CPB / TILE; ++tile) {
        const int jt = j0 + tile * TILE;
        __syncthreads();                               // cnt init / prev tile done
#pragma unroll
        for (int c = tid; c < TILE; c += 512) {        // stage 1024 candidates
            const float* src = P + (size_t)(jt + c) * 3;
            sxy[c] = make_float2(src[0], src[1]);
            szz[c] = src[2];
        }
        __syncthreads();

        const int c0 = wq * CPWT;
#pragma unroll 8
        for (int t = 0; t < CPWT; ++t) {
            const int c = c0 + t;
            const float2 cc = sxy[c];                  // ds_read_b64 broadcast
            const float dx = qx - cc.x;
            const float dy = qy - cc.y;
            const float dz = qz - szz[c];
            const float d  = fmaf(dx, dx, fmaf(dy, dy, dz * dz));
            if (d <= tauUpF) {                         // float-space superset filter
                const uint32_t key = (__float_as_uint(d) & ~IDXMASK) | (uint32_t)(jt + c);
                const uint32_t old = atomicAdd(&cnt[lane], 1u);
                if (old < CAPQ) lists[lane * LSTR + old] = key;
            }
        }
    }
    __syncthreads();

    // write-out: counts + keys, query-contiguous layout [qid][hb][slot]
    if (tid < 64) cntG[(size_t)qidG * HB + hb] = cnt[tid];
    const uint32_t mycnt = umin32(cnt[lane], CAPQ);
    uint32_t* __restrict__ dst = keysG + (size_t)qidG * (HB * CAPQ) + (size_t)hb * CAPQ;
    for (int s = wq; s < (int)mycnt; s += WPB)
        dst[s] = lists[lane * LSTR + s];
}

// ---------------- kernel 3: parallel merge (4 waves / 64 queries) + loss ----------------
__global__ __launch_bounds__(256) void plap_merge_loss(
    const float* __restrict__ p1, const float* __restrict__ p2,
    const uint32_t* __restrict__ keysG, const uint32_t* __restrict__ cntG,
    float* __restrict__ out)
{
    __shared__ uint32_t sk[HB * K1 * 64];              // 11264 B, lane-major
    const int ql = threadIdx.x & 63;
    const int w  = threadIdx.x >> 6;                   // 0..3 == hb
    const int wu = __builtin_amdgcn_readfirstlane(w);
    const int qid = blockIdx.x * 64 + ql;              // 0..NTOT-1
    const int b   = qid >> 13;
    const int qi  = qid & (NQ - 1);
    const float* __restrict__ P1 = p1 + (size_t)b * NQ * 3;
    const float* __restrict__ P2 = p2 + (size_t)b * NQ * 3;

    const float qx = P1[qi * 3 + 0];
    const float qy = P1[qi * 3 + 1];
    const float qz = P1[qi * 3 + 2];

    uint32_t F[K1];
#pragma unroll
    for (int s = 0; s < K1; ++s) F[s] = 0xFFFFFFFFu;

    const uint32_t c = cntG[(size_t)qid * HB + wu];
    if (c <= CAPQ) {
        const uint32_t* __restrict__ src =
            keysG + (size_t)qid * (HB * CAPQ) + (size_t)wu * CAPQ;
        for (uint32_t s = 0; s < c; ++s) insert11(F, src[s]);
    } else {
        // exact fallback (P ~ 1e-11): rescan this quarter
        for (int j = wu * CPB; j < (wu + 1) * CPB; ++j) {
            const float dx = qx - P1[j * 3 + 0];
            const float dy = qy - P1[j * 3 + 1];
            const float dz = qz - P1[j * 3 + 2];
            const float d  = fmaf(dx, dx, fmaf(dy, dy, dz * dz));
            insert11(F, (__float_as_uint(d) & ~IDXMASK) | (uint32_t)j);
        }
    }

#pragma unroll
    for (int s = 0; s < K1; ++s) sk[(wu * K1 + s) * 64 + ql] = F[s];
    for (int st = 1; st < HB; st <<= 1) {
        __syncthreads();
        if ((wu & (2 * st - 1)) == 0) {
#pragma unroll
            for (int e = 0; e < K1; ++e) insert11(F, sk[((wu + st) * K1 + e) * 64 + ql]);
            if (2 * st < HB) {
#pragma unroll
                for (int s = 0; s < K1; ++s) sk[(wu * K1 + s) * 64 + ql] = F[s];
            }
        }
    }

    if (wu == 0) {
        float s1x = 0.f, s1y = 0.f, s1z = 0.f, s2x = 0.f, s2y = 0.f, s2z = 0.f;
#pragma unroll
        for (int s = 1; s < K1; ++s) {                 // F[0] = self (d = 0)
            const int n = (int)(F[s] & IDXMASK);
            s1x += P1[n * 3 + 0]; s1y += P1[n * 3 + 1]; s1z += P1[n * 3 + 2];
            s2x += P2[n * 3 + 0]; s2y += P2[n * 3 + 1]; s2z += P2[n * 3 + 2];
        }
        const float invk = 1.0f / (float)KNN;
        const float lx = (s1x * invk - qx) - (s2x * invk - P2[qi * 3 + 0]);
        const float ly = (s1y * invk - qy) - (s2y * invk - P2[qi * 3 + 1]);
        const float lz = (s1z * invk - qz) - (s2z * invk - P2[qi * 3 + 2]);
        float acc = fabsf(lx) + fabsf(ly) + fabsf(lz);
#pragma unroll
        for (int off = 32; off > 0; off >>= 1)
            acc += __shfl_down(acc, off, 64);
        if (ql == 0) atomicAdd(out, acc * (1.0f / (float)(NTOT * 3)));
    }
}

extern "C" void kernel_launch(void* const* d_in, const int* in_sizes, int n_in,
                              void* d_out, int out_size, void* d_ws, size_t ws_size,
                              hipStream_t stream) {
    const float* p1 = (const float*)d_in[0];
    const float* p2 = (const float*)d_in[1];
    float* out      = (float*)d_out;

    // ws: tau (64 KB) | cnt (256 KB) | keys (NTOT*HB*CAPQ*4 = 10.5 MB)
    uint32_t* tauG  = (uint32_t*)d_ws;
    uint32_t* cntG  = tauG + NTOT;
    uint32_t* keysG = cntG + (size_t)NTOT * HB;

    plap_tau <<<dim3(NGRP), dim3(TW * 64), 0, stream>>>(p1, tauG, out);
    plap_scan<<<dim3(NGRP * HB), dim3(WPB * 64), 0, stream>>>(p1, tauG, keysG, cntG);
    plap_merge_loss<<<dim3(NGRP), dim3(256), 0, stream>>>(p1, p2, keysG, cntG, out);
}